// Round 7
// baseline (300.881 us; speedup 1.0000x reference)
//
#include <hip/hip_runtime.h>
#include <math.h>

namespace {

constexpr int H = 512;
constexpr int L = 4096;
constexpr int REPG = 8;  // gather accumulator replicas
constexpr int REPS = 4;  // colsum accumulator replicas

// ws float offsets
constexpr int WS_SU   = 0;                     // REPS*H
constexpr int WS_SL   = WS_SU + REPS * H;      // REPS*H
constexpr int WS_G    = WS_SL + REPS * H;      // REPG*4*H
constexpr int WS_IHV  = WS_G + REPG * 4 * H;   // H
constexpr int WS_ACC  = WS_IHV + H;            // 1 float
constexpr int WS_CNT  = WS_ACC + 1;            // 1 int (bilinear last-block)
constexpr int WS_DONE = WS_CNT + 1;            // 1 int (producer done-count)
constexpr int WS_TOT  = WS_DONE + 1;

constexpr int NGATHER = 128;  // 32 rows each
constexpr int NWIH    = 8;    // 64 rows each
constexpr int NBLIN   = 128;  // colsum slice + 8 (mat,h) wave-tasks each
constexpr int NGRID   = NGATHER + NWIH + NBLIN;          // 264
constexpr int DONE_TARGET = NGATHER + NWIH + NBLIN;      // every block signals once

__device__ inline float wave_reduce(float v) {
#pragma unroll
    for (int off = 32; off; off >>= 1) v += __shfl_xor(v, off, 64);
    return v;
}

__device__ inline void signal_done(int* done, int t) {
    __syncthreads();               // all waves' mem ops drained (vmcnt at barrier)
    if (t == 0) {
        __threadfence();           // release to device scope
        atomicAdd(done, 1);
    }
}

__global__ __launch_bounds__(512) void fused_k(
    const float* __restrict__ tu, const float* __restrict__ tl,
    const float* __restrict__ lu, const float* __restrict__ ll,
    const int* __restrict__ loc, const float* __restrict__ table,
    const float* __restrict__ Wsu, const float* __restrict__ Wsl,
    const float* __restrict__ Wih, const float* __restrict__ hx,
    const float* __restrict__ Wtu, const float* __restrict__ Wtl,
    float* __restrict__ ws, float* __restrict__ out) {
    const int b = blockIdx.x;
    const int t = threadIdx.x;
    int* const done = reinterpret_cast<int*>(ws) + WS_DONE;

    if (b < NGATHER) {
        // ---- gather: g_rep[v][j] += coef_v(i) * table[loc[i]][j] ----
        const int rep = b & (REPG - 1);
        float aa = 0.f, ab = 0.f, ag = 0.f, ad = 0.f;
        const int row0 = b * (L / NGATHER);
#pragma unroll 16
        for (int r = 0; r < L / NGATHER; ++r) {
            const int row = row0 + r;
            const float tuv = tu[row], tlv = tl[row];
            const float luv = lu[row], llv = ll[row];
            const float ti = 1.f / (tuv + tlv), li = 1.f / (luv + llv);
            const float Tu = tuv * ti, Tl = tlv * ti;
            const float Lu = luv * li, Ll = llv * li;
            const float e = table[(size_t)loc[row] * H + t];
            aa += Lu * Tu * e;
            ab += Lu * Tl * e;
            ag += Ll * Tu * e;
            ad += Ll * Tl * e;
        }
        float* g = ws + WS_G + rep * (4 * H);
        atomicAdd(g + 0 * H + t, aa);
        atomicAdd(g + 1 * H + t, ab);
        atomicAdd(g + 2 * H + t, ag);
        atomicAdd(g + 3 * H + t, ad);
        signal_done(done, t);
    } else if (b < NGATHER + NWIH) {
        // ---- ihv[row] = W_ih[row,:] . hx ----
        const int wb = b - NGATHER;
        const int lane = t & 63, wid = t >> 6;
        const int j = lane * 8;
        const float4 xA = *reinterpret_cast<const float4*>(hx + j);
        const float4 xB = *reinterpret_cast<const float4*>(hx + j + 4);
#pragma unroll
        for (int r = 0; r < 8; ++r) {
            const int row = wb * 64 + wid * 8 + r;
            const float4 wA = *reinterpret_cast<const float4*>(Wih + (size_t)row * H + j);
            const float4 wB = *reinterpret_cast<const float4*>(Wih + (size_t)row * H + j + 4);
            float a = wA.x * xA.x + wA.y * xA.y + wA.z * xA.z + wA.w * xA.w
                    + wB.x * xB.x + wB.y * xB.y + wB.z * xB.z + wB.w * xB.w;
            a = wave_reduce(a);
            if (lane == 0) ws[WS_IHV + row] = a;
        }
        signal_done(done, t);
    } else {
        // ---- bilinear block: colsum contribution, prefetch W row, spin, finish ----
        const int cb = b - NGATHER - NWIH;  // [0, 128)
        const int lane = t & 63, wid = t >> 6;

        // (1) colsum slice: 8 rows of Wsu or Wsl
        {
            const int mat = cb >> 6;
            const int q = cb & 63;
            const int m0 = q * (H / 64);
            const int rep = q & (REPS - 1);
            const float* W = mat ? Wsl : Wsu;
            float acc = 0.f;
#pragma unroll
            for (int r = 0; r < H / 64; ++r) acc += W[(size_t)(m0 + r) * H + t];
            atomicAdd(ws + (mat ? WS_SL : WS_SU) + rep * H + t, acc);
        }
        signal_done(done, t);

        // (2) prefetch this wave's Wtu/Wtl row while producers run
        const int gw = cb * 8 + wid;   // [0, 1024)
        const int mat = gw >> 9;       // 0: Wtu, 1: Wtl
        const int h = gw & (H - 1);
        const float* W = mat ? Wtl : Wtu;
        const int v1 = mat ? 1 : 0;    // pairs with su
        const int v2 = mat ? 3 : 2;    // pairs with sl
        const int j = lane * 8;
        const float4 wA = *reinterpret_cast<const float4*>(W + (size_t)h * H + j);
        const float4 wB = *reinterpret_cast<const float4*>(W + (size_t)h * H + j + 4);

        // (3) wait for all producers (bounded spin; device-scope RMW read)
        if (t == 0) {
            int it = 0;
            while (atomicAdd(done, 0) < DONE_TARGET && it < 10000000) {
                ++it;
                __builtin_amdgcn_s_sleep(8);
            }
        }
        __syncthreads();
        __threadfence();  // acquire: invalidate stale cached copies

        // (4) replica sums + bilinear dot
        float suh = 0.f, slh = 0.f;
#pragma unroll
        for (int rp = 0; rp < REPS; ++rp) {
            suh += ws[WS_SU + rp * H + h];
            slh += ws[WS_SL + rp * H + h];
        }
        float a1[8] = {0, 0, 0, 0, 0, 0, 0, 0};
        float a2[8] = {0, 0, 0, 0, 0, 0, 0, 0};
#pragma unroll
        for (int rp = 0; rp < REPG; ++rp) {
            const float* g1 = ws + WS_G + (rp * 4 + v1) * H + j;
            const float* g2 = ws + WS_G + (rp * 4 + v2) * H + j;
            const float4 x0 = *reinterpret_cast<const float4*>(g1);
            const float4 x1 = *reinterpret_cast<const float4*>(g1 + 4);
            const float4 y0 = *reinterpret_cast<const float4*>(g2);
            const float4 y1 = *reinterpret_cast<const float4*>(g2 + 4);
            a1[0] += x0.x; a1[1] += x0.y; a1[2] += x0.z; a1[3] += x0.w;
            a1[4] += x1.x; a1[5] += x1.y; a1[6] += x1.z; a1[7] += x1.w;
            a2[0] += y0.x; a2[1] += y0.y; a2[2] += y0.z; a2[3] += y0.w;
            a2[4] += y1.x; a2[5] += y1.y; a2[6] += y1.z; a2[7] += y1.w;
        }
        float acc = wA.x * (suh * a1[0] + slh * a2[0])
                  + wA.y * (suh * a1[1] + slh * a2[1])
                  + wA.z * (suh * a1[2] + slh * a2[2])
                  + wA.w * (suh * a1[3] + slh * a2[3])
                  + wB.x * (suh * a1[4] + slh * a2[4])
                  + wB.y * (suh * a1[5] + slh * a2[5])
                  + wB.z * (suh * a1[6] + slh * a2[6])
                  + wB.w * (suh * a1[7] + slh * a2[7]);
        acc = wave_reduce(acc);

        // (5) block reduce -> ACC atomic; last block does the sigmoid
        __shared__ float wp[8];
        __shared__ float accs;
        __shared__ int lastf;
        if (lane == 0) wp[wid] = acc;
        __syncthreads();
        if (t == 0) {
            float s = 0.f;
#pragma unroll
            for (int w = 0; w < 8; ++w) s += wp[w];
            atomicAdd(ws + WS_ACC, s);
            __threadfence();
            const int old = atomicAdd(reinterpret_cast<int*>(ws) + WS_CNT, 1);
            lastf = (old == NBLIN - 1) ? 1 : 0;
        }
        __syncthreads();
        if (lastf) {
            if (t == 0) accs = atomicAdd(ws + WS_ACC, 0.0f);  // read at coherence point
            __syncthreads();
            const float x = accs + ws[WS_IHV + t];
            out[t] = 1.f / (1.f + expf(-x));
        }
    }
}

}  // namespace

extern "C" void kernel_launch(void* const* d_in, const int* in_sizes, int n_in,
                              void* d_out, int out_size, void* d_ws, size_t ws_size,
                              hipStream_t stream) {
    const float* tu    = (const float*)d_in[0];
    const float* tl    = (const float*)d_in[1];
    const float* lu    = (const float*)d_in[2];
    const float* ll    = (const float*)d_in[3];
    const int*   loc   = (const int*)d_in[4];
    const float* hx    = (const float*)d_in[5];
    const float* Wih   = (const float*)d_in[6];
    const float* Wtu   = (const float*)d_in[7];
    const float* Wtl   = (const float*)d_in[8];
    const float* Wsu   = (const float*)d_in[9];
    const float* Wsl   = (const float*)d_in[10];
    const float* table = (const float*)d_in[11];
    float* ws  = (float*)d_ws;
    float* out = (float*)d_out;

    hipMemsetAsync(ws, 0, WS_TOT * sizeof(float), stream);
    fused_k<<<NGRID, 512, 0, stream>>>(tu, tl, lu, ll, loc, table,
                                       Wsu, Wsl, Wih, hx, Wtu, Wtl, ws, out);
}